// Round 3
// baseline (468.872 us; speedup 1.0000x reference)
//
#include <hip/hip_runtime.h>
#include <math.h>

#define Bn 8
#define Hn 256
#define Wn 256

// Load a 3x10 window (rows h-1..h+1, cols w0-1..w0+8), zero-padded borders.
// w0 is a multiple of 8 so the middle 8 cols are two aligned float4s.
__device__ __forceinline__ void load_win10(const float* __restrict__ plane,
                                           int h, int w0, float win[3][10]) {
#pragma unroll
  for (int r = 0; r < 3; ++r) {
    int hh = h - 1 + r;
    bool okh = (unsigned)hh < (unsigned)Hn;
    const float* row = plane + hh * Wn;
    if (okh) {
      float4 m0 = *(const float4*)(row + w0);
      float4 m1 = *(const float4*)(row + w0 + 4);
      win[r][0] = (w0 > 0) ? row[w0 - 1] : 0.f;
      win[r][1] = m0.x; win[r][2] = m0.y; win[r][3] = m0.z; win[r][4] = m0.w;
      win[r][5] = m1.x; win[r][6] = m1.y; win[r][7] = m1.z; win[r][8] = m1.w;
      win[r][9] = (w0 + 8 < Wn) ? row[w0 + 8] : 0.f;
    } else {
#pragma unroll
      for (int c = 0; c < 10; ++c) win[r][c] = 0.f;
    }
  }
}

// Kernel A: fused per-neighbor conv1(2->64,3x3)+ReLU -> conv2(64->1,1x1)
// -> sigmoid -> gate neighbor. Writes "combined" (B,7,H,W) into ws.
//
// R3: 8 pixels/thread (was 4). R2 was LDS-throughput-bound: 5 ds_read_b128
// per channel-iter = 240 cyc/CU of LDS pipe vs 160 cyc of VALU issue per
// SIMD. At 8 px the same weight reads amortize over 320 VALU cyc -> VALU
// bound. Grid: 6 nbr x 256 blocks = 1536 (6 blocks/CU).
__global__ __launch_bounds__(256, 4) void sim_kernel(
    const float* __restrict__ x,   // (8,7,256,256)
    const float* __restrict__ W1,  // (6,64,2,3,3)
    const float* __restrict__ b1,  // (6,64)
    const float* __restrict__ W2,  // (6,1,64,1,1)
    const float* __restrict__ b2,  // (6,1)
    float* __restrict__ comb)      // (8,7,256,256)
{
  __shared__ float4 sw4[64 * 5];

  int n  = blockIdx.x / 256;    // neighbor 0..5
  int pb = blockIdx.x & 255;    // pixel block 0..255

  // Stage weights for this neighbor. LDS layout per channel c: 20 floats =
  // [wBase(9), wCheck(9), b1, W2]; channel roles pre-swapped for n>=3 so the
  // inner loop is uniform (slot 0..8 always multiplies BASE).
  for (int t = threadIdx.x; t < 64 * 5; t += 256) {
    int c = t / 5, j = t - c * 5;
    int nc = (n << 6) + c;
    float v[4];
#pragma unroll
    for (int e = 0; e < 4; ++e) {
      int kk = 4 * j + e;  // 0..19
      float val;
      if (kk < 18) {
        int i = kk / 9, k = kk - i * 9;
        int isrc = (n < 3) ? i : 1 - i;
        val = W1[nc * 18 + isrc * 9 + k];
      } else if (kk == 18) {
        val = b1[nc];
      } else {
        val = W2[nc];
      }
      v[e] = val;
    }
    sw4[t] = make_float4(v[0], v[1], v[2], v[3]);
  }
  __syncthreads();

  int idx = pb * 256 + threadIdx.x;  // over B*H*W/8 = 65536
  int w0 = (idx & 31) << 3;
  int h  = (idx >> 5) & (Hn - 1);
  int b  = idx >> 13;

  const float* xb = x + (size_t)b * 7 * Hn * Wn;
  float* cb = comb + (size_t)b * 7 * Hn * Wn;

  float bwin[3][10];
  load_win10(xb + 3 * Hn * Wn, h, w0, bwin);

  // combined channel 3 = base (center taps) — written once, by n==0 blocks
  if (n == 0) {
    float* p = cb + 3 * Hn * Wn + h * Wn + w0;
    *(float4*)(p) = make_float4(bwin[1][1], bwin[1][2], bwin[1][3], bwin[1][4]);
    *(float4*)(p + 4) =
        make_float4(bwin[1][5], bwin[1][6], bwin[1][7], bwin[1][8]);
  }

  int cc = (n < 3) ? n : n + 1;
  float cwin[3][10];
  load_win10(xb + (size_t)cc * Hn * Wn, h, w0, cwin);

  float s[8];
#pragma unroll
  for (int p = 0; p < 8; ++p) s[p] = 0.f;

#pragma unroll 2
  for (int c = 0; c < 64; ++c) {
    float4 A = sw4[c * 5 + 0];
    float4 Bq = sw4[c * 5 + 1];
    float4 C = sw4[c * 5 + 2];
    float4 D = sw4[c * 5 + 3];
    float4 E = sw4[c * 5 + 4];
    float wb[9] = {A.x, A.y, A.z, A.w, Bq.x, Bq.y, Bq.z, Bq.w, C.x};
    float wc[9] = {C.y, C.z, C.w, D.x, D.y, D.z, D.w, E.x, E.y};
    float bias = E.z, w2v = E.w;

    float a[8];
#pragma unroll
    for (int p = 0; p < 8; ++p) a[p] = bias;
#pragma unroll
    for (int dy = 0; dy < 3; ++dy) {
#pragma unroll
      for (int dx = 0; dx < 3; ++dx) {
        float wbv = wb[dy * 3 + dx];
        float wcv = wc[dy * 3 + dx];
#pragma unroll
        for (int p = 0; p < 8; ++p) a[p] = fmaf(wbv, bwin[dy][p + dx], a[p]);
#pragma unroll
        for (int p = 0; p < 8; ++p) a[p] = fmaf(wcv, cwin[dy][p + dx], a[p]);
      }
    }
#pragma unroll
    for (int p = 0; p < 8; ++p) s[p] = fmaf(w2v, fmaxf(a[p], 0.f), s[p]);
  }

  float bb = b2[n];
  float g[8];
#pragma unroll
  for (int p = 0; p < 8; ++p) g[p] = 1.f / (1.f + expf(-(s[p] + bb)));

  float* p = cb + (size_t)cc * Hn * Wn + h * Wn + w0;
  *(float4*)(p) = make_float4(g[0] * cwin[1][1], g[1] * cwin[1][2],
                              g[2] * cwin[1][3], g[3] * cwin[1][4]);
  *(float4*)(p + 4) = make_float4(g[4] * cwin[1][5], g[5] * cwin[1][6],
                                  g[6] * cwin[1][7], g[7] * cwin[1][8]);
}

// Kernel B: final mixing conv (7->7, 3x3, SAME).
// R3: 2 pixels/thread -> 1024 blocks (4 blocks/CU, 16 waves/CU); R2 ran only
// 512 blocks (2/CU) and its 7 serialized load->compute phases were
// latency-bound at 2 waves/SIMD.
__global__ __launch_bounds__(256, 8) void mix_kernel(
    const float* __restrict__ comb,  // (8,7,256,256)
    const float* __restrict__ Wm,    // (7,7,3,3)
    const float* __restrict__ bm,    // (7,)
    float* __restrict__ out)         // (8,7,256,256)
{
  __shared__ float sW[7 * 7 * 12];  // [oc][ic][12], taps in [0..8]
  __shared__ float sb[7];
  for (int t = threadIdx.x; t < 7 * 7 * 9; t += 256) {
    int oi = t / 9, k = t - oi * 9;
    sW[oi * 12 + k] = Wm[t];
  }
  if (threadIdx.x < 7) sb[threadIdx.x] = bm[threadIdx.x];
  __syncthreads();

  int idx = blockIdx.x * 256 + threadIdx.x;  // over B*H*W/2 = 262144
  int w0 = (idx & 127) << 1;
  int h  = (idx >> 7) & (Hn - 1);
  int b  = idx >> 15;
  const float* cbase = comb + (size_t)b * 7 * Hn * Wn;

  float acc[7][2];
#pragma unroll
  for (int oc = 0; oc < 7; ++oc) {
    float bv = sb[oc];
    acc[oc][0] = bv;
    acc[oc][1] = bv;
  }

  for (int ic = 0; ic < 7; ++ic) {
    // 3x4 window: rows h-1..h+1, cols w0-1..w0+2
    float win[3][4];
#pragma unroll
    for (int r = 0; r < 3; ++r) {
      int hh = h - 1 + r;
      bool okh = (unsigned)hh < (unsigned)Hn;
      const float* row = cbase + (size_t)ic * Hn * Wn + hh * Wn;
      if (okh) {
        float2 mid = *(const float2*)(row + w0);
        win[r][0] = (w0 > 0) ? row[w0 - 1] : 0.f;
        win[r][1] = mid.x;
        win[r][2] = mid.y;
        win[r][3] = (w0 + 2 < Wn) ? row[w0 + 2] : 0.f;
      } else {
        win[r][0] = win[r][1] = win[r][2] = win[r][3] = 0.f;
      }
    }
#pragma unroll
    for (int oc = 0; oc < 7; ++oc) {
      const float* wp = &sW[(oc * 7 + ic) * 12];
      float4 t1 = *(const float4*)(wp);
      float4 t2 = *(const float4*)(wp + 4);
      float w8 = wp[8];
      float wv[9] = {t1.x, t1.y, t1.z, t1.w, t2.x, t2.y, t2.z, t2.w, w8};
#pragma unroll
      for (int dy = 0; dy < 3; ++dy) {
#pragma unroll
        for (int dx = 0; dx < 3; ++dx) {
          float wvv = wv[dy * 3 + dx];
          acc[oc][0] = fmaf(wvv, win[dy][0 + dx], acc[oc][0]);
          acc[oc][1] = fmaf(wvv, win[dy][1 + dx], acc[oc][1]);
        }
      }
    }
  }

  float* ob = out + (size_t)b * 7 * Hn * Wn + h * Wn + w0;
#pragma unroll
  for (int oc = 0; oc < 7; ++oc)
    *(float2*)(ob + (size_t)oc * Hn * Wn) = make_float2(acc[oc][0], acc[oc][1]);
}

extern "C" void kernel_launch(void* const* d_in, const int* in_sizes, int n_in,
                              void* d_out, int out_size, void* d_ws, size_t ws_size,
                              hipStream_t stream) {
  const float* x  = (const float*)d_in[0];
  const float* W1 = (const float*)d_in[1];
  const float* b1 = (const float*)d_in[2];
  const float* W2 = (const float*)d_in[3];
  const float* b2 = (const float*)d_in[4];
  const float* Wm = (const float*)d_in[5];
  const float* bm = (const float*)d_in[6];
  float* out  = (float*)d_out;
  float* comb = (float*)d_ws;  // 8*7*256*256 floats = 14.7 MB

  sim_kernel<<<6 * 256, 256, 0, stream>>>(x, W1, b1, W2, b2, comb);
  mix_kernel<<<1024, 256, 0, stream>>>(comb, Wm, bm, out);
}

// Round 4
// 180.067 us; speedup vs baseline: 2.6039x; 2.6039x over previous
//
#include <hip/hip_runtime.h>
#include <math.h>

#define Bn 8
#define Hn 256
#define Wn 256

// Load a 3x10 window (rows h-1..h+1, cols w0-1..w0+8), zero-padded borders.
// w0 is a multiple of 8 so the middle 8 cols are two aligned float4s.
__device__ __forceinline__ void load_win10(const float* __restrict__ plane,
                                           int h, int w0, float win[3][10]) {
#pragma unroll
  for (int r = 0; r < 3; ++r) {
    int hh = h - 1 + r;
    bool okh = (unsigned)hh < (unsigned)Hn;
    const float* row = plane + hh * Wn;
    if (okh) {
      float4 m0 = *(const float4*)(row + w0);
      float4 m1 = *(const float4*)(row + w0 + 4);
      win[r][0] = (w0 > 0) ? row[w0 - 1] : 0.f;
      win[r][1] = m0.x; win[r][2] = m0.y; win[r][3] = m0.z; win[r][4] = m0.w;
      win[r][5] = m1.x; win[r][6] = m1.y; win[r][7] = m1.z; win[r][8] = m1.w;
      win[r][9] = (w0 + 8 < Wn) ? row[w0 + 8] : 0.f;
    } else {
#pragma unroll
      for (int c = 0; c < 10; ++c) win[r][c] = 0.f;
    }
  }
}

// Kernel A: fused per-neighbor conv1(2->64,3x3)+ReLU -> conv2(64->1,1x1)
// -> sigmoid -> gate neighbor. Writes "combined" (B,7,H,W) into ws.
//
// R4: __launch_bounds__(256) with NO min-waves arg. R3's (256,4) capped the
// register budget at 128; with the 8-px structure (~110 live VGPRs) that
// risks scratch demotion (mix_kernel demonstrably hit this with (256,8):
// 914 MB of scratch HBM traffic). Natural allocation (~110 VGPR) still gives
// 4 waves/EU without any forced spills.
__global__ __launch_bounds__(256) void sim_kernel(
    const float* __restrict__ x,   // (8,7,256,256)
    const float* __restrict__ W1,  // (6,64,2,3,3)
    const float* __restrict__ b1,  // (6,64)
    const float* __restrict__ W2,  // (6,1,64,1,1)
    const float* __restrict__ b2,  // (6,1)
    float* __restrict__ comb)      // (8,7,256,256)
{
  __shared__ float4 sw4[64 * 5];

  int n  = blockIdx.x / 256;    // neighbor 0..5
  int pb = blockIdx.x & 255;    // pixel block 0..255

  // Stage weights for this neighbor. LDS layout per channel c: 20 floats =
  // [wBase(9), wCheck(9), b1, W2]; channel roles pre-swapped for n>=3 so the
  // inner loop is uniform (slot 0..8 always multiplies BASE).
  for (int t = threadIdx.x; t < 64 * 5; t += 256) {
    int c = t / 5, j = t - c * 5;
    int nc = (n << 6) + c;
    float v[4];
#pragma unroll
    for (int e = 0; e < 4; ++e) {
      int kk = 4 * j + e;  // 0..19
      float val;
      if (kk < 18) {
        int i = kk / 9, k = kk - i * 9;
        int isrc = (n < 3) ? i : 1 - i;
        val = W1[nc * 18 + isrc * 9 + k];
      } else if (kk == 18) {
        val = b1[nc];
      } else {
        val = W2[nc];
      }
      v[e] = val;
    }
    sw4[t] = make_float4(v[0], v[1], v[2], v[3]);
  }
  __syncthreads();

  int idx = pb * 256 + threadIdx.x;  // over B*H*W/8 = 65536
  int w0 = (idx & 31) << 3;
  int h  = (idx >> 5) & (Hn - 1);
  int b  = idx >> 13;

  const float* xb = x + (size_t)b * 7 * Hn * Wn;
  float* cb = comb + (size_t)b * 7 * Hn * Wn;

  float bwin[3][10];
  load_win10(xb + 3 * Hn * Wn, h, w0, bwin);

  // combined channel 3 = base (center taps) — written once, by n==0 blocks
  if (n == 0) {
    float* p = cb + 3 * Hn * Wn + h * Wn + w0;
    *(float4*)(p) = make_float4(bwin[1][1], bwin[1][2], bwin[1][3], bwin[1][4]);
    *(float4*)(p + 4) =
        make_float4(bwin[1][5], bwin[1][6], bwin[1][7], bwin[1][8]);
  }

  int cc = (n < 3) ? n : n + 1;
  float cwin[3][10];
  load_win10(xb + (size_t)cc * Hn * Wn, h, w0, cwin);

  float s[8];
#pragma unroll
  for (int p = 0; p < 8; ++p) s[p] = 0.f;

#pragma unroll 2
  for (int c = 0; c < 64; ++c) {
    float4 A = sw4[c * 5 + 0];
    float4 Bq = sw4[c * 5 + 1];
    float4 C = sw4[c * 5 + 2];
    float4 D = sw4[c * 5 + 3];
    float4 E = sw4[c * 5 + 4];
    float wb[9] = {A.x, A.y, A.z, A.w, Bq.x, Bq.y, Bq.z, Bq.w, C.x};
    float wc[9] = {C.y, C.z, C.w, D.x, D.y, D.z, D.w, E.x, E.y};
    float bias = E.z, w2v = E.w;

    float a[8];
#pragma unroll
    for (int p = 0; p < 8; ++p) a[p] = bias;
#pragma unroll
    for (int dy = 0; dy < 3; ++dy) {
#pragma unroll
      for (int dx = 0; dx < 3; ++dx) {
        float wbv = wb[dy * 3 + dx];
        float wcv = wc[dy * 3 + dx];
#pragma unroll
        for (int p = 0; p < 8; ++p) a[p] = fmaf(wbv, bwin[dy][p + dx], a[p]);
#pragma unroll
        for (int p = 0; p < 8; ++p) a[p] = fmaf(wcv, cwin[dy][p + dx], a[p]);
      }
    }
#pragma unroll
    for (int p = 0; p < 8; ++p) s[p] = fmaf(w2v, fmaxf(a[p], 0.f), s[p]);
  }

  float bb = b2[n];
  float g[8];
#pragma unroll
  for (int p = 0; p < 8; ++p) g[p] = 1.f / (1.f + expf(-(s[p] + bb)));

  float* p = cb + (size_t)cc * Hn * Wn + h * Wn + w0;
  *(float4*)(p) = make_float4(g[0] * cwin[1][1], g[1] * cwin[1][2],
                              g[2] * cwin[1][3], g[3] * cwin[1][4]);
  *(float4*)(p + 4) = make_float4(g[4] * cwin[1][5], g[5] * cwin[1][6],
                                  g[6] * cwin[1][7], g[7] * cwin[1][8]);
}

// Kernel B: final mixing conv (7->7, 3x3, SAME). 4 pixels/thread.
//
// R4 rewrite after the R3 scratch disaster (914 MB HBM, VALUBusy 1.9%):
//  - no LDS at all: weights/bias read with wave-uniform indices directly from
//    global -> s_load into SGPRs (scalar pipe; FMA takes the SGPR operand).
//  - ic loop fully unrolled: every array index is compile-time constant ->
//    guaranteed SROA, acc[] lives in VGPRs.
//  - __launch_bounds__(256) only — no forced register cap, no demotion.
__global__ __launch_bounds__(256) void mix_kernel(
    const float* __restrict__ comb,  // (8,7,256,256)
    const float* __restrict__ Wm,    // (7,7,3,3)
    const float* __restrict__ bm,    // (7,)
    float* __restrict__ out)         // (8,7,256,256)
{
  int idx = blockIdx.x * 256 + threadIdx.x;  // over B*H*W/4 = 131072
  int w0 = (idx & 63) << 2;
  int h  = (idx >> 6) & (Hn - 1);
  int b  = idx >> 14;
  const float* cbase = comb + (size_t)b * 7 * Hn * Wn;

  float acc[7][4];
#pragma unroll
  for (int oc = 0; oc < 7; ++oc) {
    float bv = bm[oc];  // uniform -> s_load
#pragma unroll
    for (int p = 0; p < 4; ++p) acc[oc][p] = bv;
  }

#pragma unroll
  for (int ic = 0; ic < 7; ++ic) {
    // 3x6 window: rows h-1..h+1, cols w0-1..w0+4
    float win[3][6];
    const float* plane = cbase + (size_t)ic * Hn * Wn;
#pragma unroll
    for (int r = 0; r < 3; ++r) {
      int hh = h - 1 + r;
      bool okh = (unsigned)hh < (unsigned)Hn;
      const float* row = plane + hh * Wn;
      if (okh) {
        float4 mid = *(const float4*)(row + w0);
        win[r][0] = (w0 > 0) ? row[w0 - 1] : 0.f;
        win[r][1] = mid.x; win[r][2] = mid.y;
        win[r][3] = mid.z; win[r][4] = mid.w;
        win[r][5] = (w0 + 4 < Wn) ? row[w0 + 4] : 0.f;
      } else {
        win[r][0] = win[r][1] = win[r][2] = 0.f;
        win[r][3] = win[r][4] = win[r][5] = 0.f;
      }
    }
#pragma unroll
    for (int oc = 0; oc < 7; ++oc) {
      const float* wp = Wm + (oc * 7 + ic) * 9;  // uniform -> s_load
#pragma unroll
      for (int dy = 0; dy < 3; ++dy) {
#pragma unroll
        for (int dx = 0; dx < 3; ++dx) {
          float wvv = wp[dy * 3 + dx];
#pragma unroll
          for (int p = 0; p < 4; ++p)
            acc[oc][p] = fmaf(wvv, win[dy][p + dx], acc[oc][p]);
        }
      }
    }
  }

  float* ob = out + (size_t)b * 7 * Hn * Wn + h * Wn + w0;
#pragma unroll
  for (int oc = 0; oc < 7; ++oc)
    *(float4*)(ob + (size_t)oc * Hn * Wn) =
        make_float4(acc[oc][0], acc[oc][1], acc[oc][2], acc[oc][3]);
}

extern "C" void kernel_launch(void* const* d_in, const int* in_sizes, int n_in,
                              void* d_out, int out_size, void* d_ws, size_t ws_size,
                              hipStream_t stream) {
  const float* x  = (const float*)d_in[0];
  const float* W1 = (const float*)d_in[1];
  const float* b1 = (const float*)d_in[2];
  const float* W2 = (const float*)d_in[3];
  const float* b2 = (const float*)d_in[4];
  const float* Wm = (const float*)d_in[5];
  const float* bm = (const float*)d_in[6];
  float* out  = (float*)d_out;
  float* comb = (float*)d_ws;  // 8*7*256*256 floats = 14.7 MB

  sim_kernel<<<6 * 256, 256, 0, stream>>>(x, W1, b1, W2, b2, comb);
  mix_kernel<<<512, 256, 0, stream>>>(comb, Wm, bm, out);
}